// Round 1
// baseline (240.304 us; speedup 1.0000x reference)
//
#include <hip/hip_runtime.h>
#include <math.h>

#define N_PTS 50000
#define C_DIM 64
#define K_RAD 32
#define K_KNN 10
#define E_RAD (N_PTS * K_RAD)

// ---------------- K1: per-edge rigid weight ----------------
// w_e = sigmoid(-(||R0[d] @ pos0[s] + t0[d] - x0[s]||^2) + 0.01)
// dst structure is repeat(arange(N), 32) -> d = e >> 5.
__global__ void edge_weight_kernel(const float* __restrict__ x0,
                                   const float* __restrict__ pos0,
                                   const float* __restrict__ R0,
                                   const float* __restrict__ t0,
                                   const int* __restrict__ src,
                                   float* __restrict__ wgt) {
    int e = blockIdx.x * blockDim.x + threadIdx.x;
    if (e >= E_RAD) return;
    int s = src[e];
    int d = e >> 5;
    const float* R = R0 + d * 9;
    float px = pos0[s * 3 + 0], py = pos0[s * 3 + 1], pz = pos0[s * 3 + 2];
    float r0 = R[0] * px + R[1] * py + R[2] * pz + t0[d * 3 + 0] - x0[s * 3 + 0];
    float r1 = R[3] * px + R[4] * py + R[5] * pz + t0[d * 3 + 1] - x0[s * 3 + 1];
    float r2 = R[6] * px + R[7] * py + R[8] * pz + t0[d * 3 + 2] - x0[s * 3 + 2];
    float dsq = r0 * r0 + r1 * r1 + r2 * r2;
    // sigmoid(-dsq + 0.01) = 1 / (1 + exp(dsq - 0.01))
    wgt[e] = 1.0f / (1.0f + expf(dsq - 0.01f));
}

// ---------------- K2: layer 1 (one-hot input) ----------------
// One wave per node, lane = channel c.
// m1[d][c] = max(0, max_e w_e * (assign01[src(e)] == c))
__global__ void layer1_kernel(const int* __restrict__ src,
                              const int* __restrict__ assign,
                              const float* __restrict__ wgt,
                              float* __restrict__ m1,
                              float* __restrict__ sum1) {
    int wave = (blockIdx.x * blockDim.x + threadIdx.x) >> 6;
    int lane = threadIdx.x & 63;
    if (wave >= N_PTS) return;
    int base = wave * K_RAD;
    int sl = src[base + (lane & 31)];
    float wl = wgt[base + (lane & 31)];
    int al = assign[sl];
    float m = 0.0f;
#pragma unroll
    for (int e = 0; e < K_RAD; ++e) {
        int a_e = __shfl(al, e);
        float w_e = __shfl(wl, e);
        m = fmaxf(m, (a_e == lane) ? w_e : 0.0f);
    }
    m1[wave * C_DIM + lane] = m;
    float s = m;
#pragma unroll
    for (int off = 32; off > 0; off >>= 1) s += __shfl_down(s, off);
    if (lane == 0) sum1[wave] = s;
}

// ---------------- K3: generic layer ----------------
// out[d][c] = max(0, max_e w_e * xin[src(e)][c]); also writes row sum.
__global__ void layer_kernel(const int* __restrict__ src,
                             const float* __restrict__ wgt,
                             const float* __restrict__ xin,
                             float* __restrict__ xout,
                             float* __restrict__ sum_out) {
    int wave = (blockIdx.x * blockDim.x + threadIdx.x) >> 6;
    int lane = threadIdx.x & 63;
    if (wave >= N_PTS) return;
    int base = wave * K_RAD;
    int sl = src[base + (lane & 31)];
    float wl = wgt[base + (lane & 31)];
    float m = 0.0f;
#pragma unroll
    for (int e = 0; e < K_RAD; ++e) {
        int s_e = __shfl(sl, e);
        float w_e = __shfl(wl, e);
        m = fmaxf(m, w_e * xin[s_e * C_DIM + lane]);  // coalesced 256B/edge
    }
    xout[wave * C_DIM + lane] = m;
    float s = m;
#pragma unroll
    for (int off = 32; off > 0; off >>= 1) s += __shfl_down(s, off);
    if (lane == 0) sum_out[wave] = s;
}

// ---------------- K4: layer 3 + fused confidence ----------------
// m3 == m4 == m5, so conf = sigmoid(sum1 + sum2 + 3*sum3 - 17)
__global__ void layer3_conf_kernel(const int* __restrict__ src,
                                   const float* __restrict__ wgt,
                                   const float* __restrict__ xin,
                                   float* __restrict__ xout,
                                   const float* __restrict__ sum1,
                                   const float* __restrict__ sum2,
                                   float* __restrict__ conf) {
    int wave = (blockIdx.x * blockDim.x + threadIdx.x) >> 6;
    int lane = threadIdx.x & 63;
    if (wave >= N_PTS) return;
    int base = wave * K_RAD;
    int sl = src[base + (lane & 31)];
    float wl = wgt[base + (lane & 31)];
    float m = 0.0f;
#pragma unroll
    for (int e = 0; e < K_RAD; ++e) {
        int s_e = __shfl(sl, e);
        float w_e = __shfl(wl, e);
        m = fmaxf(m, w_e * xin[s_e * C_DIM + lane]);
    }
    xout[wave * C_DIM + lane] = m;
    float s = m;
#pragma unroll
    for (int off = 32; off > 0; off >>= 1) s += __shfl_down(s, off);
    if (lane == 0) {
        float tot = sum1[wave] + sum2[wave] + 3.0f * s - 17.0f;
        conf[wave] = 1.0f / (1.0f + expf(-tot));
    }
}

// ---------------- K5: weighted average over knn + rigid transform ----------------
// knn_dst = repeat(arange(N), 10) -> node t's edges are [t*10, t*10+10)
__global__ void wavg_kernel(const int* __restrict__ knn_src,
                            const float* __restrict__ conf,
                            const float* __restrict__ R0,
                            const float* __restrict__ t0,
                            const float* __restrict__ pos0,
                            float* __restrict__ out) {
    int t = blockIdx.x * blockDim.x + threadIdx.x;
    if (t >= N_PTS) return;
    float nR[9] = {0, 0, 0, 0, 0, 0, 0, 0, 0};
    float nt0 = 0.0f, nt1 = 0.0f, nt2 = 0.0f;
    float den = 1e-8f;
    for (int j = 0; j < K_KNN; ++j) {
        int s = knn_src[t * K_KNN + j];
        float c = conf[s];
        const float* Rs = R0 + s * 9;
#pragma unroll
        for (int k = 0; k < 9; ++k) nR[k] += c * Rs[k];
        nt0 += c * t0[s * 3 + 0];
        nt1 += c * t0[s * 3 + 1];
        nt2 += c * t0[s * 3 + 2];
        den += c;
    }
    float inv = 1.0f / den;
    float Ro[9];
#pragma unroll
    for (int k = 0; k < 9; ++k) Ro[k] = nR[k] * inv;
    float to0 = nt0 * inv, to1 = nt1 * inv, to2 = nt2 * inv;
    float px = pos0[t * 3 + 0], py = pos0[t * 3 + 1], pz = pos0[t * 3 + 2];
    float xo0 = Ro[0] * px + Ro[1] * py + Ro[2] * pz + to0;
    float xo1 = Ro[3] * px + Ro[4] * py + Ro[5] * pz + to1;
    float xo2 = Ro[6] * px + Ro[7] * py + Ro[8] * pz + to2;
    // Output tuple concatenated flat: x_out [N,3], R_out [N,3,3], t_out [N,3]
    out[t * 3 + 0] = xo0;
    out[t * 3 + 1] = xo1;
    out[t * 3 + 2] = xo2;
    float* Rout = out + N_PTS * 3;
#pragma unroll
    for (int k = 0; k < 9; ++k) Rout[t * 9 + k] = Ro[k];
    float* tout = out + N_PTS * 3 + N_PTS * 9;
    tout[t * 3 + 0] = to0;
    tout[t * 3 + 1] = to1;
    tout[t * 3 + 2] = to2;
}

extern "C" void kernel_launch(void* const* d_in, const int* in_sizes, int n_in,
                              void* d_out, int out_size, void* d_ws, size_t ws_size,
                              hipStream_t stream) {
    const float* x0 = (const float*)d_in[0];
    const float* pos0 = (const float*)d_in[1];
    const float* R0 = (const float*)d_in[2];
    const float* t0 = (const float*)d_in[3];
    const int* assign01 = (const int*)d_in[4];
    const int* radius_src = (const int*)d_in[5];
    // d_in[6] = radius_dst (structure known: repeat(arange(N), 32))
    const int* knn_src = (const int*)d_in[7];
    // d_in[8] = knn_dst (repeat(arange(N), 10))

    float* ws = (float*)d_ws;
    float* wgt = ws;                     // E_RAD        = 1,600,000
    float* mA = wgt + E_RAD;             // N*C          = 3,200,000
    float* mB = mA + N_PTS * C_DIM;      // N*C          = 3,200,000
    float* sum1 = mB + N_PTS * C_DIM;    // N            =    50,000
    float* sum2 = sum1 + N_PTS;          // N
    float* conf = sum2 + N_PTS;          // N
    float* out = (float*)d_out;

    // K1: edge weights
    edge_weight_kernel<<<(E_RAD + 255) / 256, 256, 0, stream>>>(
        x0, pos0, R0, t0, radius_src, wgt);

    // K2: m1 (one-hot input) -> mA, sum1
    int layer_blocks = (N_PTS * 64 + 255) / 256;  // one wave per node
    layer1_kernel<<<layer_blocks, 256, 0, stream>>>(
        radius_src, assign01, wgt, mA, sum1);

    // K3: m2 -> mB, sum2
    layer_kernel<<<layer_blocks, 256, 0, stream>>>(
        radius_src, wgt, mA, mB, sum2);

    // K4: m3 -> mA (reuse), conf fused
    layer3_conf_kernel<<<layer_blocks, 256, 0, stream>>>(
        radius_src, wgt, mB, mA, sum1, sum2, conf);

    // K5: weighted average + final transform -> d_out
    wavg_kernel<<<(N_PTS + 255) / 256, 256, 0, stream>>>(
        knn_src, conf, R0, t0, pos0, out);
}

// Round 2
// 187.930 us; speedup vs baseline: 1.2787x; 1.2787x over previous
//
#include <hip/hip_runtime.h>
#include <hip/hip_fp16.h>
#include <math.h>

#define N_PTS 50000
#define C_DIM 64
#define K_RAD 32
#define K_KNN 10
#define E_RAD (N_PTS * K_RAD)

// ---------------- K2': fused edge-weight + layer 1 (one-hot input) --------
// One wave per node. Lanes 0..31 compute the rigid weight for edge
// (node*32 + lane) inline and persist it (f32) for K3/K4. All 64 lanes then
// build m1[node][lane] = max_e w_e * [assign[src_e] == lane].
__global__ void ew_layer1_kernel(const float* __restrict__ x0,
                                 const float* __restrict__ pos0,
                                 const float* __restrict__ R0,
                                 const float* __restrict__ t0,
                                 const int* __restrict__ src,
                                 const int* __restrict__ assign,
                                 float* __restrict__ wgt,
                                 __half* __restrict__ m1,
                                 float* __restrict__ sum1) {
    int wave = (blockIdx.x * blockDim.x + threadIdx.x) >> 6;
    int lane = threadIdx.x & 63;
    if (wave >= N_PTS) return;
    int base = wave * K_RAD;
    int el = lane & 31;
    int s = src[base + el];
    int a = assign[s];
    float w = 0.0f;
    if (lane < 32) {
        const float* R = R0 + wave * 9;
        float px = pos0[s * 3 + 0], py = pos0[s * 3 + 1], pz = pos0[s * 3 + 2];
        float r0 = R[0] * px + R[1] * py + R[2] * pz + t0[wave * 3 + 0] - x0[s * 3 + 0];
        float r1 = R[3] * px + R[4] * py + R[5] * pz + t0[wave * 3 + 1] - x0[s * 3 + 1];
        float r2 = R[6] * px + R[7] * py + R[8] * pz + t0[wave * 3 + 2] - x0[s * 3 + 2];
        float dsq = r0 * r0 + r1 * r1 + r2 * r2;
        w = 1.0f / (1.0f + expf(dsq - 0.01f));
        wgt[base + lane] = w;
    }
    float m = 0.0f;
#pragma unroll
    for (int e = 0; e < K_RAD; ++e) {
        int a_e = __shfl(a, e);
        float w_e = __shfl(w, e);
        m = fmaxf(m, (a_e == lane) ? w_e : 0.0f);
    }
    // pack channels (2*el, 2*el+1) into a half2 store from lanes 0..31
    float mlo = __shfl(m, 2 * el);
    float mhi = __shfl(m, 2 * el + 1);
    if (lane < 32) {
        *(__half2*)(m1 + wave * C_DIM + 2 * el) = __floats2half2_rn(mlo, mhi);
    }
    float ssum = m;
#pragma unroll
    for (int off = 32; off > 0; off >>= 1) ssum += __shfl_down(ssum, off);
    if (lane == 0) sum1[wave] = ssum;
}

// ---------------- K3': generic fp16 layer ----------------
// One wave per node. lane = (eh, cl): eh = lane>>5 picks even/odd edges,
// cl = lane&31 picks channel pair (2cl, 2cl+1). 16 loop trips, each a
// 4 B half2 gather per lane (256 B per wave-instruction across both halves).
__global__ void layer_h_kernel(const int* __restrict__ src,
                               const float* __restrict__ wgt,
                               const __half* __restrict__ xin,
                               __half* __restrict__ xout,
                               float* __restrict__ sum_out) {
    int wave = (blockIdx.x * blockDim.x + threadIdx.x) >> 6;
    int lane = threadIdx.x & 63;
    if (wave >= N_PTS) return;
    int base = wave * K_RAD;
    int el = lane & 31;
    int eh = lane >> 5;
    int sl = src[base + el];
    float wl = wgt[base + el];
    float m0 = 0.0f, m1v = 0.0f;
#pragma unroll
    for (int p = 0; p < 16; ++p) {
        int e = p * 2 + eh;
        int s_e = __shfl(sl, e);
        float w_e = __shfl(wl, e);
        __half2 h = *(const __half2*)(xin + s_e * C_DIM + el * 2);
        float2 v = __half22float2(h);
        m0 = fmaxf(m0, w_e * v.x);
        m1v = fmaxf(m1v, w_e * v.y);
    }
    m0 = fmaxf(m0, __shfl_xor(m0, 32));
    m1v = fmaxf(m1v, __shfl_xor(m1v, 32));
    if (lane < 32) {
        *(__half2*)(xout + wave * C_DIM + el * 2) = __floats2half2_rn(m0, m1v);
    }
    float s = m0 + m1v;
#pragma unroll
    for (int off = 16; off > 0; off >>= 1) s += __shfl_down(s, off);
    if (lane == 0) sum_out[wave] = s;
}

// ---------------- K4': fp16 layer 3 + fused confidence ----------------
// m3 == m4 == m5  =>  conf = sigmoid(sum1 + sum2 + 3*sum3 - 17)
__global__ void layer3_conf_h_kernel(const int* __restrict__ src,
                                     const float* __restrict__ wgt,
                                     const __half* __restrict__ xin,
                                     const float* __restrict__ sum1,
                                     const float* __restrict__ sum2,
                                     float* __restrict__ conf) {
    int wave = (blockIdx.x * blockDim.x + threadIdx.x) >> 6;
    int lane = threadIdx.x & 63;
    if (wave >= N_PTS) return;
    int base = wave * K_RAD;
    int el = lane & 31;
    int eh = lane >> 5;
    int sl = src[base + el];
    float wl = wgt[base + el];
    float m0 = 0.0f, m1v = 0.0f;
#pragma unroll
    for (int p = 0; p < 16; ++p) {
        int e = p * 2 + eh;
        int s_e = __shfl(sl, e);
        float w_e = __shfl(wl, e);
        __half2 h = *(const __half2*)(xin + s_e * C_DIM + el * 2);
        float2 v = __half22float2(h);
        m0 = fmaxf(m0, w_e * v.x);
        m1v = fmaxf(m1v, w_e * v.y);
    }
    m0 = fmaxf(m0, __shfl_xor(m0, 32));
    m1v = fmaxf(m1v, __shfl_xor(m1v, 32));
    float s = m0 + m1v;
#pragma unroll
    for (int off = 16; off > 0; off >>= 1) s += __shfl_down(s, off);
    if (lane == 0) {
        float tot = sum1[wave] + sum2[wave] + 3.0f * s - 17.0f;
        conf[wave] = 1.0f / (1.0f + expf(-tot));
    }
}

// ---------------- K5: weighted average over knn + rigid transform --------
__global__ void wavg_kernel(const int* __restrict__ knn_src,
                            const float* __restrict__ conf,
                            const float* __restrict__ R0,
                            const float* __restrict__ t0,
                            const float* __restrict__ pos0,
                            float* __restrict__ out) {
    int t = blockIdx.x * blockDim.x + threadIdx.x;
    if (t >= N_PTS) return;
    float nR[9] = {0, 0, 0, 0, 0, 0, 0, 0, 0};
    float nt0 = 0.0f, nt1 = 0.0f, nt2 = 0.0f;
    float den = 1e-8f;
    for (int j = 0; j < K_KNN; ++j) {
        int s = knn_src[t * K_KNN + j];
        float c = conf[s];
        const float* Rs = R0 + s * 9;
#pragma unroll
        for (int k = 0; k < 9; ++k) nR[k] += c * Rs[k];
        nt0 += c * t0[s * 3 + 0];
        nt1 += c * t0[s * 3 + 1];
        nt2 += c * t0[s * 3 + 2];
        den += c;
    }
    float inv = 1.0f / den;
    float Ro[9];
#pragma unroll
    for (int k = 0; k < 9; ++k) Ro[k] = nR[k] * inv;
    float to0 = nt0 * inv, to1 = nt1 * inv, to2 = nt2 * inv;
    float px = pos0[t * 3 + 0], py = pos0[t * 3 + 1], pz = pos0[t * 3 + 2];
    out[t * 3 + 0] = Ro[0] * px + Ro[1] * py + Ro[2] * pz + to0;
    out[t * 3 + 1] = Ro[3] * px + Ro[4] * py + Ro[5] * pz + to1;
    out[t * 3 + 2] = Ro[6] * px + Ro[7] * py + Ro[8] * pz + to2;
    float* Rout = out + N_PTS * 3;
#pragma unroll
    for (int k = 0; k < 9; ++k) Rout[t * 9 + k] = Ro[k];
    float* tout = out + N_PTS * 3 + N_PTS * 9;
    tout[t * 3 + 0] = to0;
    tout[t * 3 + 1] = to1;
    tout[t * 3 + 2] = to2;
}

extern "C" void kernel_launch(void* const* d_in, const int* in_sizes, int n_in,
                              void* d_out, int out_size, void* d_ws, size_t ws_size,
                              hipStream_t stream) {
    const float* x0 = (const float*)d_in[0];
    const float* pos0 = (const float*)d_in[1];
    const float* R0 = (const float*)d_in[2];
    const float* t0 = (const float*)d_in[3];
    const int* assign01 = (const int*)d_in[4];
    const int* radius_src = (const int*)d_in[5];
    const int* knn_src = (const int*)d_in[7];

    float* ws = (float*)d_ws;
    float* wgt = ws;                          // E_RAD f32     = 6.4 MB
    float* sum1 = wgt + E_RAD;                // N f32
    float* sum2 = sum1 + N_PTS;               // N f32
    float* conf = sum2 + N_PTS;               // N f32
    __half* mA = (__half*)(conf + N_PTS);     // N*C half      = 6.4 MB
    __half* mB = mA + N_PTS * C_DIM;          // N*C half      = 6.4 MB
    float* out = (float*)d_out;

    int layer_blocks = (N_PTS * 64 + 255) / 256;  // one wave per node

    // K2': edge weights + m1 -> wgt, mA, sum1
    ew_layer1_kernel<<<layer_blocks, 256, 0, stream>>>(
        x0, pos0, R0, t0, radius_src, assign01, wgt, mA, sum1);

    // K3': m2 -> mB, sum2
    layer_h_kernel<<<layer_blocks, 256, 0, stream>>>(
        radius_src, wgt, mA, mB, sum2);

    // K4': m3 + fused conf
    layer3_conf_h_kernel<<<layer_blocks, 256, 0, stream>>>(
        radius_src, wgt, mB, sum1, sum2, conf);

    // K5: weighted average + final transform -> d_out
    wavg_kernel<<<(N_PTS + 255) / 256, 256, 0, stream>>>(
        knn_src, conf, R0, t0, pos0, out);
}

// Round 4
// 173.301 us; speedup vs baseline: 1.3866x; 1.0844x over previous
//
#include <hip/hip_runtime.h>
#include <hip/hip_fp16.h>
#include <math.h>

#define N_PTS 50000
#define C_DIM 64
#define K_RAD 32
#define K_KNN 10
#define E_RAD (N_PTS * K_RAD)

// ROCm hip_fp16.h has no __hmax2; emit packed fp16 max directly.
__device__ inline __half2 hmax2(__half2 a, __half2 b) {
    __half2 d;
    asm("v_pk_max_f16 %0, %1, %2" : "=v"(d) : "v"(a), "v"(b));
    return d;
}

// ---------------- K2: fused edge-weight + layer 1 (one-hot input) --------
// One wave per node. Lanes 0..31 compute the rigid weight for edge
// (node*32 + lane), pack (src<<16)|half(w) for later kernels, and scatter
// w into a per-wave 64-entry LDS array with atomicMax (int-bits max ==
// float max for w > 0). Each lane then reads its channel. No shfl loop.
__global__ void ew_layer1_kernel(const float* __restrict__ x0,
                                 const float* __restrict__ pos0,
                                 const float* __restrict__ R0,
                                 const float* __restrict__ t0,
                                 const int* __restrict__ src,
                                 const int* __restrict__ assign,
                                 unsigned int* __restrict__ packed,
                                 __half* __restrict__ m1,
                                 float* __restrict__ sum1) {
    __shared__ int lm[4][C_DIM];
    int wave = (blockIdx.x * blockDim.x + threadIdx.x) >> 6;
    int lane = threadIdx.x & 63;
    int wslot = threadIdx.x >> 6;
    if (wave >= N_PTS) return;
    lm[wslot][lane] = 0;
    int base = wave * K_RAD;
    float w = 0.0f;
    int a = 0;
    if (lane < 32) {
        int s = src[base + lane];
        a = assign[s];
        const float* R = R0 + wave * 9;
        float px = pos0[s * 3 + 0], py = pos0[s * 3 + 1], pz = pos0[s * 3 + 2];
        float r0 = R[0] * px + R[1] * py + R[2] * pz + t0[wave * 3 + 0] - x0[s * 3 + 0];
        float r1 = R[3] * px + R[4] * py + R[5] * pz + t0[wave * 3 + 1] - x0[s * 3 + 1];
        float r2 = R[6] * px + R[7] * py + R[8] * pz + t0[wave * 3 + 2] - x0[s * 3 + 2];
        float dsq = r0 * r0 + r1 * r1 + r2 * r2;
        w = 1.0f / (1.0f + expf(dsq - 0.01f));
        unsigned int wb = (unsigned int)__half_as_ushort(__float2half_rn(w));
        packed[base + lane] = ((unsigned int)s << 16) | wb;
    }
    __syncthreads();
    if (lane < 32) atomicMax(&lm[wslot][a], __float_as_int(w));
    __syncthreads();
    float m = __int_as_float(lm[wslot][lane]);
    if (lane < 32) {
        float lo = __int_as_float(lm[wslot][2 * lane]);
        float hi = __int_as_float(lm[wslot][2 * lane + 1]);
        *(__half2*)(m1 + wave * C_DIM + 2 * lane) = __floats2half2_rn(lo, hi);
    }
    float ssum = m;
#pragma unroll
    for (int off = 32; off > 0; off >>= 1) ssum += __shfl_down(ssum, off);
    if (lane == 0) sum1[wave] = ssum;
}

// ---------------- K3: packed fp16 layer ----------------
// One wave per node. lane = (eh, cl): eh = lane>>5 picks even/odd edges,
// cl = lane&31 picks channel pair. One bpermute per iteration (packed
// src+weight word); packed-fp16 mul/max (v_pk_*_f16).
__global__ void layer_pk_kernel(const unsigned int* __restrict__ packed,
                                const __half* __restrict__ xin,
                                __half* __restrict__ xout,
                                float* __restrict__ sum_out) {
    int wave = (blockIdx.x * blockDim.x + threadIdx.x) >> 6;
    int lane = threadIdx.x & 63;
    if (wave >= N_PTS) return;
    int el = lane & 31;
    int eh = lane >> 5;
    unsigned int pk = packed[wave * K_RAD + el];
    __half2 m = __float2half2_rn(0.0f);
#pragma unroll
    for (int p = 0; p < 16; ++p) {
        unsigned int pe = (unsigned int)__shfl((int)pk, p * 2 + eh);
        const __half2* row = (const __half2*)(xin + (pe >> 16) * C_DIM);
        __half2 h = row[el];
        __half2 w2 = __half2half2(__ushort_as_half((unsigned short)(pe & 0xffffu)));
        m = hmax2(m, __hmul2(w2, h));
    }
    int mi = *(int*)&m;
    int mo = __shfl_xor(mi, 32);
    m = hmax2(m, *(__half2*)&mo);
    if (lane < 32) ((__half2*)(xout + wave * C_DIM))[el] = m;
    float2 v = __half22float2(m);
    float s = v.x + v.y;
#pragma unroll
    for (int off = 16; off > 0; off >>= 1) s += __shfl_down(s, off);
    if (lane == 0) sum_out[wave] = s;
}

// ---------------- K4: packed fp16 layer 3 + fused confidence ----------------
// m3 == m4 == m5  =>  conf = sigmoid(sum1 + sum2 + 3*sum3 - 17)
__global__ void layer3_conf_pk_kernel(const unsigned int* __restrict__ packed,
                                      const __half* __restrict__ xin,
                                      const float* __restrict__ sum1,
                                      const float* __restrict__ sum2,
                                      float* __restrict__ conf) {
    int wave = (blockIdx.x * blockDim.x + threadIdx.x) >> 6;
    int lane = threadIdx.x & 63;
    if (wave >= N_PTS) return;
    int el = lane & 31;
    int eh = lane >> 5;
    unsigned int pk = packed[wave * K_RAD + el];
    __half2 m = __float2half2_rn(0.0f);
#pragma unroll
    for (int p = 0; p < 16; ++p) {
        unsigned int pe = (unsigned int)__shfl((int)pk, p * 2 + eh);
        const __half2* row = (const __half2*)(xin + (pe >> 16) * C_DIM);
        __half2 h = row[el];
        __half2 w2 = __half2half2(__ushort_as_half((unsigned short)(pe & 0xffffu)));
        m = hmax2(m, __hmul2(w2, h));
    }
    int mi = *(int*)&m;
    int mo = __shfl_xor(mi, 32);
    m = hmax2(m, *(__half2*)&mo);
    float2 v = __half22float2(m);
    float s = v.x + v.y;
#pragma unroll
    for (int off = 16; off > 0; off >>= 1) s += __shfl_down(s, off);
    if (lane == 0) {
        float tot = sum1[wave] + sum2[wave] + 3.0f * s - 17.0f;
        conf[wave] = 1.0f / (1.0f + expf(-tot));
    }
}

// ---------------- K5: weighted average over knn + rigid transform --------
__global__ void wavg_kernel(const int* __restrict__ knn_src,
                            const float* __restrict__ conf,
                            const float* __restrict__ R0,
                            const float* __restrict__ t0,
                            const float* __restrict__ pos0,
                            float* __restrict__ out) {
    int t = blockIdx.x * blockDim.x + threadIdx.x;
    if (t >= N_PTS) return;
    float nR[9] = {0, 0, 0, 0, 0, 0, 0, 0, 0};
    float nt0 = 0.0f, nt1 = 0.0f, nt2 = 0.0f;
    float den = 1e-8f;
    for (int j = 0; j < K_KNN; ++j) {
        int s = knn_src[t * K_KNN + j];
        float c = conf[s];
        const float* Rs = R0 + s * 9;
#pragma unroll
        for (int k = 0; k < 9; ++k) nR[k] += c * Rs[k];
        nt0 += c * t0[s * 3 + 0];
        nt1 += c * t0[s * 3 + 1];
        nt2 += c * t0[s * 3 + 2];
        den += c;
    }
    float inv = 1.0f / den;
    float Ro[9];
#pragma unroll
    for (int k = 0; k < 9; ++k) Ro[k] = nR[k] * inv;
    float to0 = nt0 * inv, to1 = nt1 * inv, to2 = nt2 * inv;
    float px = pos0[t * 3 + 0], py = pos0[t * 3 + 1], pz = pos0[t * 3 + 2];
    out[t * 3 + 0] = Ro[0] * px + Ro[1] * py + Ro[2] * pz + to0;
    out[t * 3 + 1] = Ro[3] * px + Ro[4] * py + Ro[5] * pz + to1;
    out[t * 3 + 2] = Ro[6] * px + Ro[7] * py + Ro[8] * pz + to2;
    float* Rout = out + N_PTS * 3;
#pragma unroll
    for (int k = 0; k < 9; ++k) Rout[t * 9 + k] = Ro[k];
    float* tout = out + N_PTS * 3 + N_PTS * 9;
    tout[t * 3 + 0] = to0;
    tout[t * 3 + 1] = to1;
    tout[t * 3 + 2] = to2;
}

extern "C" void kernel_launch(void* const* d_in, const int* in_sizes, int n_in,
                              void* d_out, int out_size, void* d_ws, size_t ws_size,
                              hipStream_t stream) {
    const float* x0 = (const float*)d_in[0];
    const float* pos0 = (const float*)d_in[1];
    const float* R0 = (const float*)d_in[2];
    const float* t0 = (const float*)d_in[3];
    const int* assign01 = (const int*)d_in[4];
    const int* radius_src = (const int*)d_in[5];
    const int* knn_src = (const int*)d_in[7];

    unsigned int* packed = (unsigned int*)d_ws;       // E_RAD u32 = 6.4 MB
    float* sum1 = (float*)(packed + E_RAD);           // N f32
    float* sum2 = sum1 + N_PTS;                       // N f32
    float* conf = sum2 + N_PTS;                       // N f32
    __half* mA = (__half*)(conf + N_PTS);             // N*C half = 6.4 MB
    __half* mB = mA + N_PTS * C_DIM;                  // N*C half = 6.4 MB
    float* out = (float*)d_out;

    int layer_blocks = (N_PTS * 64 + 255) / 256;  // one wave per node

    // K2: edge weights + packed words + m1 -> packed, mA, sum1
    ew_layer1_kernel<<<layer_blocks, 256, 0, stream>>>(
        x0, pos0, R0, t0, radius_src, assign01, packed, mA, sum1);

    // K3: m2 -> mB, sum2
    layer_pk_kernel<<<layer_blocks, 256, 0, stream>>>(
        packed, mA, mB, sum2);

    // K4: m3 + fused conf
    layer3_conf_pk_kernel<<<layer_blocks, 256, 0, stream>>>(
        packed, mB, sum1, sum2, conf);

    // K5: weighted average + final transform -> d_out
    wavg_kernel<<<(N_PTS + 255) / 256, 256, 0, stream>>>(
        knn_src, conf, R0, t0, pos0, out);
}